// Round 5
// baseline (473.665 us; speedup 1.0000x reference)
//
#include <hip/hip_runtime.h>
#include <hip/hip_fp16.h>

#define DIMC 768
#define NH 4
#define HD 192
#define SEQ 2048
#define NBATCH 8
#define SCALE_F 0.07216878364870323f  /* 192^-0.5 */
#define LOG2E   1.4426950408889634f
#define DEFER_THR 8.0f                /* log2-domain defer-max threshold */

typedef _Float16 f16x8 __attribute__((ext_vector_type(8)));
typedef _Float16 f16x4 __attribute__((ext_vector_type(4)));
typedef float    f32x4 __attribute__((ext_vector_type(4)));

__device__ __forceinline__ f32x4 mfma16(f16x8 a, f16x8 b, f32x4 c) {
    return __builtin_amdgcn_mfma_f32_16x16x32_f16(a, b, c, 0, 0, 0);
}
__device__ __forceinline__ void gl16(const void* g, void* l) {
    __builtin_amdgcn_global_load_lds(
        (const __attribute__((address_space(1))) unsigned int*)g,
        (__attribute__((address_space(3))) unsigned int*)l, 16, 0, 0);
}
__device__ __forceinline__ float exp2_hw(float x) {
    return __builtin_amdgcn_exp2f(x);   // v_exp_f32 (base-2)
}

// ---------------------------------------------------------------------------
// cvt_w: fp32 W[768][768] -> fp16 pre-swizzled tile images.
// Image layout: ((nt*12 + kb)*128 + r)*64 + (c ^ ((r&7)<<3)).
// ---------------------------------------------------------------------------
__global__ __launch_bounds__(256)
void cvt_w(const float* __restrict__ w0, const float* __restrict__ w1,
           const float* __restrict__ w2, const float* __restrict__ w3,
           _Float16* __restrict__ o0, _Float16* __restrict__ o1,
           _Float16* __restrict__ o2, _Float16* __restrict__ o3)
{
    const float* src = (blockIdx.y == 0) ? w0 : (blockIdx.y == 1) ? w1
                     : (blockIdx.y == 2) ? w2 : w3;
    _Float16* dst = (blockIdx.y == 0) ? o0 : (blockIdx.y == 1) ? o1
                  : (blockIdx.y == 2) ? o2 : o3;
    const int e   = blockIdx.x * 256 + threadIdx.x;
    const int row = e / 192;
    const int col = (e - row * 192) * 4;
    const float4 v = *(const float4*)(src + (size_t)row * DIMC + col);
    const int nt = row >> 7, r = row & 127, kb = col >> 6, c = col & 63;
    f16x4 h = {(_Float16)v.x, (_Float16)v.y, (_Float16)v.z, (_Float16)v.w};
    *(f16x4*)(dst + ((size_t)(nt * 12 + kb) * 128 + r) * 64 + (c ^ ((r & 7) << 3))) = h;
}

// ---------------------------------------------------------------------------
// Shared MFMA compute phase for the 128x128 BK=64 GEMM (4 waves, 2x2).
// ---------------------------------------------------------------------------
__device__ __forceinline__ void gemm_compute(const _Float16* As, const _Float16* Bs,
                                             int wr, int wc, int l15, int l4,
                                             f32x4 acc[4][4])
{
    #pragma unroll
    for (int ks = 0; ks < 2; ++ks) {
        const int cb = (ks * 32 + l4 * 8) ^ ((l15 & 7) << 3);
        f16x8 af[4], bf[4];
        #pragma unroll
        for (int m = 0; m < 4; ++m)
            af[m] = *(const f16x8*)(As + (size_t)(wr * 64 + m * 16 + l15) * 64 + cb);
        #pragma unroll
        for (int n = 0; n < 4; ++n)
            bf[n] = *(const f16x8*)(Bs + (size_t)(wc * 64 + n * 16 + l15) * 64 + cb);
        #pragma unroll
        for (int m = 0; m < 4; ++m)
            #pragma unroll
            for (int n = 0; n < 4; ++n)
                acc[m][n] = mfma16(af[m], bf[n], acc[m][n]);
    }
}

// ---------------------------------------------------------------------------
// Projection GEMM: Y = A @ W.T, A fp32, Wimg fp16 swizzled image.
// MODE 0: Qh linear [bh][n][d], scaled.
// MODE 1: Kimg tile [bh*32+kt][12288]: key*192 + swz(d)
// MODE 3: Vimg tile [bh*32+kt][12288]: d*64 + swz(key)
// ---------------------------------------------------------------------------
template<int MODE>
__global__ __launch_bounds__(256, 2)
void gemm_a32(const float* __restrict__ A, const _Float16* __restrict__ Wimg,
              _Float16* __restrict__ Y, float scale)
{
    __shared__ __attribute__((aligned(16))) _Float16 As[2][8192];
    __shared__ __attribute__((aligned(16))) _Float16 Bs[2][8192];

    const int tid  = threadIdx.x;
    const int wid  = tid >> 6;
    const int lane = tid & 63;
    const int l15  = lane & 15;
    const int l4   = lane >> 4;
    const int wr   = wid >> 1;
    const int wc   = wid & 1;
    const int m0   = blockIdx.x * 128;
    const int nt   = blockIdx.y;

    const unsigned char* Wt = (const unsigned char*)(Wimg + (size_t)nt * 12 * 8192);

    f32x4 acc[4][4];
    #pragma unroll
    for (int m = 0; m < 4; ++m)
        #pragma unroll
        for (int n = 0; n < 4; ++n)
            acc[m][n] = (f32x4){0.f, 0.f, 0.f, 0.f};

    float4 rA[8];
    #pragma unroll
    for (int p = 0; p < 8; ++p) {
        const int linear = p * 256 + tid;
        const int row = linear >> 4, qc = (linear & 15) * 4;
        rA[p] = *(const float4*)(A + (size_t)(m0 + row) * DIMC + qc);
    }
    #pragma unroll
    for (int s = 0; s < 4; ++s)
        gl16(Wt + (size_t)(s * 256 + tid) * 16, &Bs[0][(s * 256 + tid) * 8]);

    for (int t = 0; t < 12; ++t) {
        const int cur = t & 1;
        if (t < 11) {
            const unsigned char* Wn = Wt + (size_t)(t + 1) * 16384;
            #pragma unroll
            for (int s = 0; s < 4; ++s)
                gl16(Wn + (size_t)(s * 256 + tid) * 16, &Bs[cur ^ 1][(s * 256 + tid) * 8]);
            asm volatile("s_waitcnt vmcnt(4)" ::: "memory");
        } else {
            asm volatile("s_waitcnt vmcnt(0)" ::: "memory");
        }
        #pragma unroll
        for (int p = 0; p < 8; ++p) {
            const int linear = p * 256 + tid;
            const int row = linear >> 4, qc = (linear & 15) * 4;
            f16x4 h = {(_Float16)rA[p].x, (_Float16)rA[p].y,
                       (_Float16)rA[p].z, (_Float16)rA[p].w};
            *(f16x4*)(&As[cur][row * 64 + (qc ^ ((row & 7) << 3))]) = h;
        }
        if (t < 11) {
            #pragma unroll
            for (int p = 0; p < 8; ++p) {
                const int linear = p * 256 + tid;
                const int row = linear >> 4, qc = (linear & 15) * 4;
                rA[p] = *(const float4*)(A + (size_t)(m0 + row) * DIMC + (t + 1) * 64 + qc);
            }
        }
        asm volatile("s_waitcnt lgkmcnt(0)" ::: "memory");
        __builtin_amdgcn_s_barrier();

        gemm_compute(&As[cur][0], &Bs[cur][0], wr, wc, l15, l4, acc);

        __builtin_amdgcn_s_barrier();
    }

    #pragma unroll
    for (int m = 0; m < 4; ++m) {
        const int rbase = m0 + wr * 64 + m * 16 + l4 * 4;
        #pragma unroll
        for (int n = 0; n < 4; ++n) {
            const int c = nt * 128 + wc * 64 + n * 16 + l15;
            const int h = c / HD;
            const int d = c - h * HD;
            #pragma unroll
            for (int j = 0; j < 4; ++j) {
                const int r   = rbase + j;
                const int b   = r >> 11;
                const int nn  = r & (SEQ - 1);
                const int kt  = nn >> 6;
                const int key = nn & 63;
                size_t idx;
                if (MODE == 0)
                    idx = ((size_t)(b * NH + h) * SEQ + nn) * HD + d;
                else {
                    const size_t tb = ((size_t)(b * NH + h) * 32 + kt) * 12288;
                    if (MODE == 1)
                        idx = tb + (size_t)key * HD + (d ^ ((key & 7) << 3));
                    else
                        idx = tb + (size_t)d * 64 + (key ^ ((d & 7) << 3));
                }
                Y[idx] = (_Float16)(acc[m][n][j] * scale);
            }
        }
    }
}

// ---------------------------------------------------------------------------
// Final GEMM: out = Ximg @ Wp.T + bias, both fp16 swizzled images via gl16.
// ---------------------------------------------------------------------------
__global__ __launch_bounds__(256, 2)
void gemm_x(const _Float16* __restrict__ Ximg, const _Float16* __restrict__ Wimg,
            float* __restrict__ out, const float* __restrict__ bias)
{
    __shared__ __attribute__((aligned(16))) _Float16 As[2][8192];
    __shared__ __attribute__((aligned(16))) _Float16 Bs[2][8192];

    const int tid  = threadIdx.x;
    const int wid  = tid >> 6;
    const int lane = tid & 63;
    const int l15  = lane & 15;
    const int l4   = lane >> 4;
    const int wr   = wid >> 1;
    const int wc   = wid & 1;
    const int mt   = blockIdx.x;
    const int nt   = blockIdx.y;

    const unsigned char* Xt = (const unsigned char*)(Ximg + (size_t)mt * 12 * 8192);
    const unsigned char* Wt = (const unsigned char*)(Wimg + (size_t)nt * 12 * 8192);

    f32x4 acc[4][4];
    #pragma unroll
    for (int m = 0; m < 4; ++m)
        #pragma unroll
        for (int n = 0; n < 4; ++n)
            acc[m][n] = (f32x4){0.f, 0.f, 0.f, 0.f};

    #pragma unroll
    for (int s = 0; s < 4; ++s) {
        gl16(Xt + (size_t)(s * 256 + tid) * 16, &As[0][(s * 256 + tid) * 8]);
        gl16(Wt + (size_t)(s * 256 + tid) * 16, &Bs[0][(s * 256 + tid) * 8]);
    }

    for (int t = 0; t < 12; ++t) {
        const int cur = t & 1;
        if (t < 11) {
            const unsigned char* Xn = Xt + (size_t)(t + 1) * 16384;
            const unsigned char* Wn = Wt + (size_t)(t + 1) * 16384;
            #pragma unroll
            for (int s = 0; s < 4; ++s) {
                gl16(Xn + (size_t)(s * 256 + tid) * 16, &As[cur ^ 1][(s * 256 + tid) * 8]);
                gl16(Wn + (size_t)(s * 256 + tid) * 16, &Bs[cur ^ 1][(s * 256 + tid) * 8]);
            }
            asm volatile("s_waitcnt vmcnt(8)" ::: "memory");
        } else {
            asm volatile("s_waitcnt vmcnt(0)" ::: "memory");
        }
        __builtin_amdgcn_s_barrier();

        gemm_compute(&As[cur][0], &Bs[cur][0], wr, wc, l15, l4, acc);

        __builtin_amdgcn_s_barrier();
    }

    #pragma unroll
    for (int m = 0; m < 4; ++m) {
        const int rbase = mt * 128 + wr * 64 + m * 16 + l4 * 4;
        #pragma unroll
        for (int n = 0; n < 4; ++n) {
            const int c = nt * 128 + wc * 64 + n * 16 + l15;
            const float bv = bias[c];
            #pragma unroll
            for (int j = 0; j < 4; ++j)
                out[(size_t)(rbase + j) * DIMC + c] = acc[m][n][j] + bv;
        }
    }
}

// ---------------------------------------------------------------------------
// Flash attention, T15 double-pipeline:
//  Per body t: softmax(t) + QK^T(t+1) interleaved (indep: different tiles),
//  then P-write + PV(t). One barrier per tile; K 3-deep, V 2-deep buffers.
//  Waves 0-7 stage K, waves 8-15 stage V (3 gl16 each).
// ---------------------------------------------------------------------------
__global__ __launch_bounds__(1024, 4)
void attn4(const _Float16* __restrict__ Qh, const _Float16* __restrict__ Kimg,
           const _Float16* __restrict__ Vimg, _Float16* __restrict__ Ximg)
{
    __shared__ __attribute__((aligned(16))) _Float16 KB[3][12288];
    __shared__ __attribute__((aligned(16))) _Float16 VB[2][12288];
    __shared__ __attribute__((aligned(16))) _Float16 Ps[16][16][72];

    const int tid  = threadIdx.x;
    const int wid  = tid >> 6;
    const int lane = tid & 63;
    const int l15  = lane & 15;
    const int l4   = lane >> 4;

    const int bid = blockIdx.x;
    const int swz = (bid & 7) * 32 + (bid >> 3);
    const int qt  = swz & 7;
    const int bh  = swz >> 3;

    const unsigned char* Kt0 = (const unsigned char*)Kimg + (size_t)bh * 32 * 24576;
    const unsigned char* Vt0 = (const unsigned char*)Vimg + (size_t)bh * 32 * 24576;

    // waves 0-7 stage K(tK) -> KB[tK%3]; waves 8-15 stage V(tV) -> VB[tV&1]
    auto stage = [&](int tK, int tV) {
        if (wid < 8) {
            if (tK < 32) {
                const unsigned char* s0 = Kt0 + (size_t)tK * 24576;
                _Float16* d0 = &KB[tK % 3][0];
                #pragma unroll
                for (int s = 0; s < 3; ++s)
                    gl16(s0 + (size_t)(s * 512 + tid) * 16, d0 + (size_t)(s * 512 + tid) * 8);
            }
        } else {
            if (tV < 32) {
                const int vt = tid - 512;
                const unsigned char* s0 = Vt0 + (size_t)tV * 24576;
                _Float16* d0 = &VB[tV & 1][0];
                #pragma unroll
                for (int s = 0; s < 3; ++s)
                    gl16(s0 + (size_t)(s * 512 + vt) * 16, d0 + (size_t)(s * 512 + vt) * 8);
            }
        }
    };

    // Q fragments (scale*log2e pre-folded by projection)
    const int q0 = qt * 256 + wid * 16;
    const size_t qbase = (size_t)bh * SEQ * HD;
    f16x8 qf[6];
    #pragma unroll
    for (int kk = 0; kk < 6; ++kk)
        qf[kk] = *(const f16x8*)(Qh + qbase + (size_t)(q0 + l15) * HD + kk * 32 + l4 * 8);
    __builtin_amdgcn_sched_barrier(0);   // pin Q loads before stage loads

    stage(0, 0);
    stage(1, 32);

    f32x4 Oacc[12];
    #pragma unroll
    for (int nd = 0; nd < 12; ++nd)
        Oacc[nd] = (f32x4){0.f, 0.f, 0.f, 0.f};
    float mrow[4], lrow[4];
    #pragma unroll
    for (int j = 0; j < 4; ++j) { mrow[j] = -1e30f; lrow[j] = 0.f; }

    auto qkt = [&](int tt, f32x4 (&p)[4]) {
        const _Float16* Kc = &KB[tt % 3][0];
        #pragma unroll
        for (int nn = 0; nn < 4; ++nn)
            p[nn] = (f32x4){0.f, 0.f, 0.f, 0.f};
        #pragma unroll
        for (int kk = 0; kk < 6; ++kk) {
            const int cb = (kk * 32 + l4 * 8) ^ ((l15 & 7) << 3);
            #pragma unroll
            for (int nn = 0; nn < 4; ++nn) {
                const f16x8 kf = *(const f16x8*)(Kc + (size_t)(nn * 16 + l15) * HD + cb);
                p[nn] = mfma16(qf[kk], kf, p[nn]);
            }
        }
    };

    asm volatile("s_waitcnt vmcnt(3)" ::: "memory");  // Q + K0 landed (V0/K1 fly)
    __builtin_amdgcn_s_barrier();
    __builtin_amdgcn_sched_barrier(0);

    f32x4 pA[4], pB[4];
    qkt(0, pA);

    auto body = [&](int t, f32x4 (&pCur)[4], f32x4 (&pNxt)[4]) {
        // ---- softmax(t) on pCur (VALU/DS) ----
        float vmax[4];
        bool need = false;
        #pragma unroll
        for (int j = 0; j < 4; ++j) {
            float v = fmaxf(fmaxf(pCur[0][j], pCur[1][j]),
                            fmaxf(pCur[2][j], pCur[3][j]));
            v = fmaxf(v, __shfl_xor(v, 1));
            v = fmaxf(v, __shfl_xor(v, 2));
            v = fmaxf(v, __shfl_xor(v, 4));
            v = fmaxf(v, __shfl_xor(v, 8));
            vmax[j] = v;
            need |= (v > mrow[j] + DEFER_THR);
        }
        if (__any(need)) {
            #pragma unroll
            for (int j = 0; j < 4; ++j) {
                const float mnew = fmaxf(mrow[j], vmax[j]);
                const float f    = exp2_hw(mrow[j] - mnew);
                mrow[j] = mnew;
                lrow[j] *= f;
                #pragma unroll
                for (int nd = 0; nd < 12; ++nd)
                    Oacc[nd][j] *= f;
            }
        }
        #pragma unroll
        for (int j = 0; j < 4; ++j) {
            float ssum = 0.f;
            #pragma unroll
            for (int nn = 0; nn < 4; ++nn) {
                const float p = exp2_hw(pCur[nn][j] - mrow[j]);
                pCur[nn][j] = p;
                ssum += p;
            }
            ssum += __shfl_xor(ssum, 1);
            ssum += __shfl_xor(ssum, 2);
            ssum += __shfl_xor(ssum, 4);
            ssum += __shfl_xor(ssum, 8);
            lrow[j] += ssum;
        }

        // ---- QK^T(t+1) (MFMA, independent of softmax above) ----
        if (t < 31) qkt(t + 1, pNxt);

        // ---- P-write + PV(t) ----
        #pragma unroll
        for (int nn = 0; nn < 4; ++nn)
            #pragma unroll
            for (int j = 0; j < 4; ++j)
                Ps[wid][l4 * 4 + j][nn * 16 + l15] = (_Float16)pCur[nn][j];

        const _Float16* Vc = &VB[t & 1][0];
        __builtin_amdgcn_s_setprio(1);
        #pragma unroll
        for (int kk2 = 0; kk2 < 2; ++kk2) {
            const f16x8 pf = *(const f16x8*)(&Ps[wid][l15][kk2 * 32 + l4 * 8]);
            const int cb = (kk2 * 32 + l4 * 8) ^ ((l15 & 7) << 3);
            #pragma unroll
            for (int nd = 0; nd < 12; ++nd) {
                const f16x8 vfr = *(const f16x8*)(Vc + (size_t)(nd * 16 + l15) * 64 + cb);
                Oacc[nd] = mfma16(pf, vfr, Oacc[nd]);
            }
        }
        __builtin_amdgcn_s_setprio(0);
    };

    for (int t2 = 0; t2 < 32; t2 += 2) {
        asm volatile("s_waitcnt vmcnt(0)" ::: "memory");
        __builtin_amdgcn_s_barrier();
        __builtin_amdgcn_sched_barrier(0);
        stage(t2 + 2, t2 + 1);
        body(t2, pA, pB);

        asm volatile("s_waitcnt vmcnt(0)" ::: "memory");
        __builtin_amdgcn_s_barrier();
        __builtin_amdgcn_sched_barrier(0);
        stage(t2 + 3, t2 + 2);
        body(t2 + 1, pB, pA);
    }

    // finalize into pre-swizzled X image
    const int b = bh >> 2;
    const int h = bh & 3;
    #pragma unroll
    for (int j = 0; j < 4; ++j) {
        const float inv = 1.f / lrow[j];
        const int qrow = q0 + l4 * 4 + j;
        const int gr   = b * SEQ + qrow;
        const int mt   = gr >> 7;
        const int r    = gr & 127;
        #pragma unroll
        for (int nd = 0; nd < 12; ++nd) {
            const int gc = h * HD + nd * 16 + l15;
            const int kb = gc >> 6;
            const int c  = gc & 63;
            Ximg[((size_t)(mt * 12 + kb) * 128 + r) * 64 + (c ^ ((r & 7) << 3))] =
                (_Float16)(Oacc[nd][j] * inv);
        }
    }
}

// ---------------------------------------------------------------------------
extern "C" void kernel_launch(void* const* d_in, const int* in_sizes, int n_in,
                              void* d_out, int out_size, void* d_ws, size_t ws_size,
                              hipStream_t stream)
{
    const float* q  = (const float*)d_in[0];
    const float* k  = (const float*)d_in[1];
    const float* v  = (const float*)d_in[2];
    const float* Wq = (const float*)d_in[3];
    const float* Wk = (const float*)d_in[4];
    const float* Wv = (const float*)d_in[5];
    const float* Wp = (const float*)d_in[6];
    const float* bp = (const float*)d_in[7];

    const size_t HSZ  = (size_t)NBATCH * NH * SEQ * HD;  // 12,582,912
    const size_t WIMG = 6 * 12 * 8192;                   // 589,824 halves
    _Float16* Qh    = (_Float16*)d_ws;
    _Float16* Kimg  = Qh + HSZ;
    _Float16* Vimg  = Kimg + HSZ;
    _Float16* Ximg  = Vimg + HSZ;
    _Float16* Wpimg = Ximg + HSZ;        // ~101.8 MB total ws
    _Float16* Wqimg = (_Float16*)d_out;  // d_out scratch until final GEMM
    _Float16* Wkimg = Wqimg + WIMG;
    _Float16* Wvimg = Wkimg + WIMG;

    dim3 blk(256);
    dim3 ggrid(128, 6);

    cvt_w<<<dim3(576, 4), blk, 0, stream>>>(Wq, Wk, Wv, Wp, Wqimg, Wkimg, Wvimg, Wpimg);
    gemm_a32<0><<<ggrid, blk, 0, stream>>>(q, Wqimg, Qh, SCALE_F * LOG2E);
    gemm_a32<1><<<ggrid, blk, 0, stream>>>(k, Wkimg, Kimg, 1.0f);
    gemm_a32<3><<<ggrid, blk, 0, stream>>>(v, Wvimg, Vimg, 1.0f);
    attn4<<<dim3(256), dim3(1024), 0, stream>>>(Qh, Kimg, Vimg, Ximg);
    gemm_x<<<ggrid, blk, 0, stream>>>(Ximg, Wpimg, (float*)d_out, bp);
}